// Round 2
// baseline (331.932 us; speedup 1.0000x reference)
//
#include <hip/hip_runtime.h>
#include <hip/hip_bf16.h>

#define N_Q 256
#define M_S 1024
#define DD 512
#define HH 512
#define BK 32
#define SA 40   // LDS row stride (shorts): 80 B = 5 x 16B groups (odd -> phases cycle all 8 banks-groups)
#define SB 40

typedef __attribute__((ext_vector_type(8))) short short8;
typedef __attribute__((ext_vector_type(8))) __bf16 bf16x8;
typedef __attribute__((ext_vector_type(16))) float f32x16;
typedef __attribute__((ext_vector_type(2))) __bf16 bf16x2;

union U8 { short8 s; bf16x8 b; };

__device__ __forceinline__ unsigned short f2bf(float f) {
  unsigned int u = __float_as_uint(f);
  u += 0x7FFFu + ((u >> 16) & 1u);
  return (unsigned short)(u >> 16);
}

__device__ __forceinline__ short8 pack8(const float* d) {
#if defined(__has_builtin) && __has_builtin(__builtin_amdgcn_cvt_pk_bf16_f32)
  short8 r;
#pragma unroll
  for (int i = 0; i < 4; ++i) {
    union { bf16x2 v; short s[2]; } u;
    u.v = __builtin_amdgcn_cvt_pk_bf16_f32(d[2 * i], d[2 * i + 1]);
    r[2 * i] = u.s[0];
    r[2 * i + 1] = u.s[1];
  }
  return r;
#else
  short8 r;
#pragma unroll
  for (int i = 0; i < 8; ++i) r[i] = (short)f2bf(d[i]);
  return r;
#endif
}

// W1 [D][H] fp32 -> w1t [H][D] bf16 (transposed), LDS-tiled for coalescing
__global__ __launch_bounds__(256) void prep_w1t(const float* __restrict__ W1,
                                                unsigned short* __restrict__ w1t) {
  __shared__ float tile[64][65];
  const int h0 = blockIdx.x * 64, d0 = blockIdx.y * 64;
  const int tx = threadIdx.x, ty = threadIdx.y;  // block (64,4)
  for (int i = ty; i < 64; i += 4)
    tile[i][tx] = W1[(d0 + i) * HH + h0 + tx];
  __syncthreads();
  for (int i = ty; i < 64; i += 4)
    w1t[(h0 + i) * DD + d0 + tx] = f2bf(tile[tx][i]);
}

// Stage one K-slab into registers: 16 diffs -> 2 bf16x8, and 32 B-shorts (one h-row)
__device__ __forceinline__ void load_stage(const float* __restrict__ erow,
                                           const float* __restrict__ srow,
                                           const unsigned short* __restrict__ brow,
                                           int k0, short8 av[2], short8 bv[4]) {
  float d[16];
  const float4* e4 = (const float4*)(erow + k0);
  const float4* s4 = (const float4*)(srow + k0);
#pragma unroll
  for (int i = 0; i < 4; ++i) {
    float4 ev = e4[i], sv = s4[i];
    d[4 * i + 0] = fabsf(ev.x - sv.x);
    d[4 * i + 1] = fabsf(ev.y - sv.y);
    d[4 * i + 2] = fabsf(ev.z - sv.z);
    d[4 * i + 3] = fabsf(ev.w - sv.w);
  }
  av[0] = pack8(d);
  av[1] = pack8(d + 8);
  const short8* b8 = (const short8*)(brow + k0);
#pragma unroll
  for (int j = 0; j < 4; ++j) bv[j] = b8[j];
}

// Block: 256 thr = 4 waves (wm = pair-half of 128, whq = h-half of 256).
// Wave tile 64 pairs x 128 h. H split 2-way over blockIdx.z; partial logits
// are atomicAdd'ed into out (zeroed by memset), finalized by logits_finalize.
__global__ __launch_bounds__(256, 2) void support_kernel(
    const float* __restrict__ emb, const float* __restrict__ sup,
    const unsigned short* __restrict__ w1t, const float* __restrict__ b1,
    const float* __restrict__ W2, const float* __restrict__ b2,
    float* __restrict__ out) {
  __shared__ short As[128 * SA];  // 10240 B
  __shared__ short Bs[256 * SB];  // 20480 B

  const int tid = threadIdx.x;
  const int lane = tid & 63;
  const int wid = tid >> 6;     // 0..3
  const int wm = wid & 1;       // pair half (64 pairs)
  const int whq = wid >> 1;     // h half (128 h)
  const int l31 = lane & 31;
  const int khalf = lane >> 5;

  const int m0 = blockIdx.x * 16;
  const int n0 = blockIdx.y * 8;
  const int hz = blockIdx.z * 256;

  // staging map: A: 2 threads per pair-row (16 k each); B: 1 h-row per thread
  const int ra = tid >> 1;                 // 0..127 pair row
  const int kh = tid & 1;                  // k half (16 elems)
  const float* erow = emb + (n0 + (ra >> 4)) * DD + kh * 16;
  const float* srow = sup + (m0 + (ra & 15)) * DD + kh * 16;
  const unsigned short* brow = w1t + (hz + tid) * DD;  // B row = tid

  f32x16 acc[2][4] = {};

  short8 av[2], bv[4];
  load_stage(erow, srow, brow, 0, av, bv);

  for (int it = 0; it < DD / BK; ++it) {
    __syncthreads();  // prev tile consumed
    *(short8*)&As[ra * SA + kh * 16] = av[0];
    *(short8*)&As[ra * SA + kh * 16 + 8] = av[1];
#pragma unroll
    for (int j = 0; j < 4; ++j)
      *(short8*)&Bs[tid * SB + j * 8] = bv[j];
    __syncthreads();  // tile visible

    if (it + 1 < DD / BK)
      load_stage(erow, srow, brow, (it + 1) * BK, av, bv);

#pragma unroll
    for (int kk = 0; kk < 2; ++kk) {
      U8 a0, a1, bf[4];
      a0.s = *(const short8*)&As[(wm * 64 + l31) * SA + kk * 16 + khalf * 8];
      a1.s = *(const short8*)&As[(wm * 64 + 32 + l31) * SA + kk * 16 + khalf * 8];
#pragma unroll
      for (int tj = 0; tj < 4; ++tj)
        bf[tj].s = *(const short8*)&Bs[(whq * 128 + tj * 32 + l31) * SB + kk * 16 + khalf * 8];
#pragma unroll
      for (int tj = 0; tj < 4; ++tj) {
        acc[0][tj] = __builtin_amdgcn_mfma_f32_32x32x16_bf16(a0.b, bf[tj].b, acc[0][tj], 0, 0, 0);
        acc[1][tj] = __builtin_amdgcn_mfma_f32_32x32x16_bf16(a1.b, bf[tj].b, acc[1][tj], 0, 0, 0);
      }
    }
  }

  // ---- epilogue: partial_nm = sum_{h in block} relu(C + b1)*W2; atomicAdd ----
  float b1v[4], w2v[4];
#pragma unroll
  for (int tj = 0; tj < 4; ++tj) {
    int h = hz + whq * 128 + tj * 32 + l31;  // C/D: col = lane&31
    b1v[tj] = b1[h];
    w2v[tj] = W2[h];
  }
  __syncthreads();
  float* psums = (float*)As;  // [128 pairs][2 h-halves]
#pragma unroll
  for (int am = 0; am < 2; ++am) {
#pragma unroll
    for (int r = 0; r < 16; ++r) {
      float s = 0.f;
#pragma unroll
      for (int tj = 0; tj < 4; ++tj)
        s += fmaxf(acc[am][tj][r] + b1v[tj], 0.f) * w2v[tj];
      s += __shfl_xor(s, 1, 64);
      s += __shfl_xor(s, 2, 64);
      s += __shfl_xor(s, 4, 64);
      s += __shfl_xor(s, 8, 64);
      s += __shfl_xor(s, 16, 64);
      if (l31 == 0) {
        int row32 = (r & 3) + 8 * (r >> 2) + 4 * khalf;  // C/D row map (m74/m101)
        psums[(wm * 64 + am * 32 + row32) * 2 + whq] = s;
      }
    }
  }
  __syncthreads();
  if (tid < 128) {
    float v = psums[tid * 2] + psums[tid * 2 + 1];
    atomicAdd(out + (n0 + (tid >> 4)) * M_S + m0 + (tid & 15), v);
  }
}

__global__ __launch_bounds__(256) void logits_finalize(float* __restrict__ out,
                                                       const float* __restrict__ b2) {
  int i = blockIdx.x * 256 + threadIdx.x;
  float t = out[i] + b2[0];
  out[i] = 1.f / (1.f + __expf(-t));
}

extern "C" void kernel_launch(void* const* d_in, const int* in_sizes, int n_in,
                              void* d_out, int out_size, void* d_ws, size_t ws_size,
                              hipStream_t stream) {
  const float* emb = (const float*)d_in[0];
  const float* sup = (const float*)d_in[1];
  const float* W1  = (const float*)d_in[2];
  const float* b1  = (const float*)d_in[3];
  const float* W2  = (const float*)d_in[4];
  const float* b2  = (const float*)d_in[5];
  float* out = (float*)d_out;
  unsigned short* w1t = (unsigned short*)d_ws;  // 512 KB

  prep_w1t<<<dim3(HH / 64, DD / 64), dim3(64, 4), 0, stream>>>(W1, w1t);
  hipMemsetAsync(d_out, 0, (size_t)N_Q * M_S * sizeof(float), stream);
  support_kernel<<<dim3(M_S / 16, N_Q / 8, 2), 256, 0, stream>>>(emb, sup, w1t, b1, W2, b2, out);
  logits_finalize<<<(N_Q * M_S) / 256, 256, 0, stream>>>(out, b2);
}